// Round 3
// baseline (707.250 us; speedup 1.0000x reference)
//
#include <hip/hip_runtime.h>

#define CDIM 256
#define HW 1024            // 32*32
#define NROWS 32768        // 32*1024
#define KCODES 1024
#define ZQ_ELEMS 8388608   // 32*256*1024
#define IDX_OFF ZQ_ELEMS
#define LOSS_OFF (ZQ_ELEMS + NROWS)
#define FLT_BIG 3.402823466e+38f

// ---- numpy-bit-exact pairwise sum of squares over 256 floats (plain) ----
__device__ __forceinline__ float np_sumsq_256(const float* __restrict__ a) {
    float half[2];
#pragma unroll
    for (int h = 0; h < 2; ++h) {
        const float* p = a + h * 128;
        float r[8];
#pragma unroll
        for (int j = 0; j < 8; ++j) r[j] = __fmul_rn(p[j], p[j]);
#pragma unroll
        for (int i = 8; i < 128; i += 8) {
#pragma unroll
            for (int j = 0; j < 8; ++j)
                r[j] = __fadd_rn(r[j], __fmul_rn(p[i + j], p[i + j]));
        }
        float ta = __fadd_rn(__fadd_rn(r[0], r[1]), __fadd_rn(r[2], r[3]));
        float tb = __fadd_rn(__fadd_rn(r[4], r[5]), __fadd_rn(r[6], r[7]));
        half[h] = __fadd_rn(ta, tb);
    }
    return __fadd_rn(half[0], half[1]);
}

// ---- same, but reading through the z_lds XOR swizzle: logical c stored at (c ^ xr) ----
__device__ __forceinline__ float np_sumsq_256_swz(const float* __restrict__ p, int xr) {
    float half[2];
#pragma unroll
    for (int h = 0; h < 2; ++h) {
        float r[8];
#pragma unroll
        for (int j = 0; j < 8; ++j) {
            float v = p[(h * 128 + j) ^ xr];
            r[j] = __fmul_rn(v, v);
        }
#pragma unroll
        for (int i = 8; i < 128; i += 8) {
#pragma unroll
            for (int j = 0; j < 8; ++j) {
                float v = p[(h * 128 + i + j) ^ xr];
                r[j] = __fadd_rn(r[j], __fmul_rn(v, v));
            }
        }
        float ta = __fadd_rn(__fadd_rn(r[0], r[1]), __fadd_rn(r[2], r[3]));
        float tb = __fadd_rn(__fadd_rn(r[4], r[5]), __fadd_rn(r[6], r[7]));
        half[h] = __fadd_rn(ta, tb);
    }
    return __fadd_rn(half[0], half[1]);
}

// ---- kernel 1: e2[k] = np-exact sum(emb[k,:]**2) ----
__global__ void __launch_bounds__(256)
e2_kernel(const float* __restrict__ emb, float* __restrict__ e2) {
    int k = blockIdx.x * blockDim.x + threadIdx.x;
    if (k >= KCODES) return;
    e2[k] = np_sumsq_256(emb + (size_t)k * CDIM);
}

// ---- kernel 2: fused distance + argmin ----
// Block: 256 threads, 32 rows x ALL 1024 codes (K fully in registers).
// lane: my = lane>>4 (0..3), kx = lane&15; kgroup = wave*16+kx (0..63).
// Thread tile: 8 rows (my+4i) x 16 codes (kgroup+64jj). acc[8][16].
// c-loop: 32 chunks of 8 c, e chunk staged to LDS each iter (single buffer).
// Swizzles: z_lds row m stores col c at (c ^ 4*(m&7)); e_lds row k stores
// 16B-half p at p^((k>>2)&1). Both make all main-loop reads conflict-free.
__global__ void __launch_bounds__(256, 2)
argmin_kernel(const float* __restrict__ z, const float* __restrict__ emb,
              const float* __restrict__ e2g, float* __restrict__ out_idx_f,
              int* __restrict__ ws_idx) {
    __shared__ __align__(16) float z_lds[32 * 256];   // 32 KB
    __shared__ __align__(16) float e_lds[1024 * 8];   // 32 KB (also z2 stash + reduce arrays)

    const int t    = threadIdx.x;
    const int lane = t & 63;
    const int wave = t >> 6;
    const int kx   = lane & 15;
    const int my   = lane >> 4;            // 0..3
    const int kgroup = wave * 16 + kx;     // 0..63
    const int xbit = (kgroup >> 2) & 1;    // e-swizzle bit, constant per thread

    const int n0  = blockIdx.x * 32;
    const int b   = n0 >> 10;
    const int hw0 = n0 & 1023;
    const float* zbase = z + (size_t)b * (CDIM * HW) + hw0;

    // ---- stage z tile [32 hw][256 c] -> z_lds[m][c ^ 4*(m&7)] ----
#pragma unroll
    for (int p = 0; p < 8; ++p) {
        int id = p * 256 + t;        // 0..2047 float4s
        int c  = id >> 3;            // 0..255
        int m4 = id & 7;
        float4 v = *(const float4*)(zbase + (size_t)c * HW + m4 * 4);
        int m0 = m4 * 4;
        z_lds[(m0 + 0) * 256 + (c ^ (4 * ((m0 + 0) & 7)))] = v.x;
        z_lds[(m0 + 1) * 256 + (c ^ (4 * ((m0 + 1) & 7)))] = v.y;
        z_lds[(m0 + 2) * 256 + (c ^ (4 * ((m0 + 2) & 7)))] = v.z;
        z_lds[(m0 + 3) * 256 + (c ^ (4 * ((m0 + 3) & 7)))] = v.w;
    }
    __syncthreads();

    // np-exact z2 per row (swizzle-aware), stash in e_lds head
    if (t < 32) e_lds[t] = np_sumsq_256_swz(&z_lds[t * 256], 4 * (t & 7));
    __syncthreads();

    float z2r[8];
#pragma unroll
    for (int i = 0; i < 8; ++i) z2r[i] = e_lds[my + 4 * i];
    __syncthreads();   // everyone has z2 before e staging overwrites e_lds

    float acc[8][16];
#pragma unroll
    for (int i = 0; i < 8; ++i)
#pragma unroll
        for (int jj = 0; jj < 16; ++jj) acc[i][jj] = 0.f;

    // staging map: sid = q*256+t -> k = q*128 + (t>>1), p = t&1 (32B per k-row,
    // lane pairs contiguous in global). LDS half-swap ps = p ^ ((k>>2)&1) = (t&1)^((t>>3)&1).
    const int kst = t >> 1;
    const int ps  = (t & 1) ^ ((t >> 3) & 1);
    const size_t gst = (size_t)kst * CDIM + (t & 1) * 4;

    // per-thread precomputed zf swizzle offsets: xr_i = 4*((my+4i)&7)
    int xr_i[8];
#pragma unroll
    for (int i = 0; i < 8; ++i) xr_i[i] = 4 * ((my + 4 * i) & 7);

    for (int u = 0; u < 32; ++u) {
        const int c0 = u * 8;

        // issue global loads for chunk u (no LDS dependency -> overlap barrier wait)
        float4 sv[8];
#pragma unroll
        for (int q = 0; q < 8; ++q)
            sv[q] = *(const float4*)(emb + (size_t)q * 128 * CDIM + gst + c0);

        __syncthreads();   // readers of chunk u-1 done
#pragma unroll
        for (int q = 0; q < 8; ++q)
            *(float4*)&e_lds[(q * 128 + kst) * 8 + ps * 4] = sv[q];
        __syncthreads();   // chunk u visible

#pragma unroll
        for (int s = 0; s < 2; ++s) {
            const int cs = c0 + 4 * s;
            float4 zf[8];
#pragma unroll
            for (int i = 0; i < 8; ++i)
                zf[i] = *(const float4*)&z_lds[(my + 4 * i) * 256 + (cs ^ xr_i[i])];
            const int esel = 4 * (s ^ xbit);
#pragma unroll
            for (int half = 0; half < 2; ++half) {
                float4 ef[8];
#pragma unroll
                for (int j = 0; j < 8; ++j)
                    ef[j] = *(const float4*)&e_lds[(kgroup + 64 * (half * 8 + j)) * 8 + esel];
#pragma unroll
                for (int i = 0; i < 8; ++i)
#pragma unroll
                    for (int j = 0; j < 8; ++j) {
                        const int jj = half * 8 + j;
                        acc[i][jj] = fmaf(zf[i].x, ef[j].x, acc[i][jj]);
                        acc[i][jj] = fmaf(zf[i].y, ef[j].y, acc[i][jj]);
                        acc[i][jj] = fmaf(zf[i].z, ef[j].z, acc[i][jj]);
                        acc[i][jj] = fmaf(zf[i].w, ef[j].w, acc[i][jj]);
                    }
            }
        }
    }

    // ---- epilogue: d = fl(fl(z2+e2) - 2*dot); jj ascending = k ascending ----
    float best_s[8];
    int   best_k[8];
#pragma unroll
    for (int i = 0; i < 8; ++i) { best_s[i] = FLT_BIG; best_k[i] = 0; }

#pragma unroll
    for (int jj = 0; jj < 16; ++jj) {
        const int kk = kgroup + 64 * jj;
        const float ek = e2g[kk];
#pragma unroll
        for (int i = 0; i < 8; ++i) {
            float t1 = __fadd_rn(z2r[i], ek);
            float d  = __fsub_rn(t1, acc[i][jj] + acc[i][jj]);
            if (d < best_s[i]) { best_s[i] = d; best_k[i] = kk; }
        }
    }

    __syncthreads();
    float* red_s = e_lds;                   // 32*64 floats
    int*   red_k = (int*)(e_lds + 2048);    // 32*64 ints
#pragma unroll
    for (int i = 0; i < 8; ++i) {
        int m = my + 4 * i;
        red_s[m * 64 + kgroup] = best_s[i];
        red_k[m * 64 + kgroup] = best_k[i];
    }
    __syncthreads();
    if (t < 32) {
        float bs = FLT_BIG;
        int bk = KCODES;
        for (int x = 0; x < 64; ++x) {
            float s = red_s[t * 64 + x];
            int  k2 = red_k[t * 64 + x];
            if (s < bs || (s == bs && k2 < bk)) { bs = s; bk = k2; }
        }
        out_idx_f[n0 + t] = (float)bk;
        ws_idx[n0 + t] = bk;
    }
}

// ---- kernel 3: gather z_q, write z_q_st, partial loss sums ----
// grid 1024 = 32 b x 32 c-groups of 8 c; thread owns 4 consecutive hw.
__global__ void __launch_bounds__(256)
gather_kernel(const float* __restrict__ z, const float* __restrict__ emb,
              const int* __restrict__ ws_idx, float* __restrict__ out_zq,
              float* __restrict__ partials) {
    const int t  = threadIdx.x;
    const int b  = blockIdx.x >> 5;
    const int cg = blockIdx.x & 31;
    const int hw4 = t * 4;

    const int4 iv = *(const int4*)&ws_idx[b * HW + hw4];
    const float* zb = z + (size_t)b * (CDIM * HW) + hw4;
    float* ob = out_zq + (size_t)b * (CDIM * HW) + hw4;
    const float* e0p = emb + (size_t)iv.x * CDIM;
    const float* e1p = emb + (size_t)iv.y * CDIM;
    const float* e2p = emb + (size_t)iv.z * CDIM;
    const float* e3p = emb + (size_t)iv.w * CDIM;

    float lsum = 0.f;
#pragma unroll
    for (int c = cg * 8; c < cg * 8 + 8; ++c) {
        float4 zv = *(const float4*)&zb[(size_t)c * HW];
        float d0 = e0p[c] - zv.x;
        float d1 = e1p[c] - zv.y;
        float d2 = e2p[c] - zv.z;
        float d3 = e3p[c] - zv.w;
        float4 ov = { zv.x + d0, zv.y + d1, zv.z + d2, zv.w + d3 };
        *(float4*)&ob[(size_t)c * HW] = ov;
        lsum = fmaf(d0, d0, lsum);
        lsum = fmaf(d1, d1, lsum);
        lsum = fmaf(d2, d2, lsum);
        lsum = fmaf(d3, d3, lsum);
    }
#pragma unroll
    for (int off = 32; off > 0; off >>= 1) lsum += __shfl_down(lsum, off);
    __shared__ float wsum[4];
    if ((t & 63) == 0) wsum[t >> 6] = lsum;
    __syncthreads();
    if (t == 0) partials[blockIdx.x] = (wsum[0] + wsum[1]) + (wsum[2] + wsum[3]);
}

// ---- kernel 4: finalize loss = 1.25 * mean(diff^2) over 1024 partials ----
__global__ void loss_kernel(const float* __restrict__ partials, float* __restrict__ out_loss) {
    const int t = threadIdx.x;
    float4 v4 = *(const float4*)&partials[t * 4];
    float v = (v4.x + v4.y) + (v4.z + v4.w);
#pragma unroll
    for (int off = 32; off > 0; off >>= 1) v += __shfl_down(v, off);
    __shared__ float wsum[4];
    if ((t & 63) == 0) wsum[t >> 6] = v;
    __syncthreads();
    if (t == 0) {
        float total = (wsum[0] + wsum[1]) + (wsum[2] + wsum[3]);
        out_loss[0] = 1.25f * total / 8388608.0f;
    }
}

extern "C" void kernel_launch(void* const* d_in, const int* in_sizes, int n_in,
                              void* d_out, int out_size, void* d_ws, size_t ws_size,
                              hipStream_t stream) {
    const float* z   = (const float*)d_in[0];
    const float* emb = (const float*)d_in[1];
    float* out = (float*)d_out;

    float* e2       = (float*)d_ws;                                   // 1024 f
    int*   ws_idx   = (int*)((char*)d_ws + 4096);                     // 32768 i32
    float* partials = (float*)((char*)d_ws + 4096 + 131072);          // 1024 f

    hipLaunchKernelGGL(e2_kernel, dim3(4), dim3(256), 0, stream, emb, e2);
    hipLaunchKernelGGL(argmin_kernel, dim3(1024), dim3(256), 0, stream,
                       z, emb, e2, out + IDX_OFF, ws_idx);
    hipLaunchKernelGGL(gather_kernel, dim3(1024), dim3(256), 0, stream,
                       z, emb, ws_idx, out, partials);
    hipLaunchKernelGGL(loss_kernel, dim3(1), dim3(256), 0, stream,
                       partials, out + LOSS_OFF);
}

// Round 4
// 673.522 us; speedup vs baseline: 1.0501x; 1.0501x over previous
//
#include <hip/hip_runtime.h>

#define CDIM 256
#define HW 1024            // 32*32
#define NROWS 32768        // 32*1024
#define KCODES 1024
#define ZQ_ELEMS 8388608   // 32*256*1024
#define IDX_OFF ZQ_ELEMS
#define LOSS_OFF (ZQ_ELEMS + NROWS)
#define FLT_BIG 3.402823466e+38f

typedef _Float16 f16;
typedef _Float16 f16x8 __attribute__((ext_vector_type(8)));
typedef float f32x4 __attribute__((ext_vector_type(4)));

// ---- numpy-bit-exact pairwise sum of squares over 256 contiguous floats ----
__device__ __forceinline__ float np_sumsq_256(const float* __restrict__ a) {
    float half[2];
#pragma unroll
    for (int h = 0; h < 2; ++h) {
        const float* p = a + h * 128;
        float r[8];
#pragma unroll
        for (int j = 0; j < 8; ++j) r[j] = __fmul_rn(p[j], p[j]);
#pragma unroll
        for (int i = 8; i < 128; i += 8) {
#pragma unroll
            for (int j = 0; j < 8; ++j)
                r[j] = __fadd_rn(r[j], __fmul_rn(p[i + j], p[i + j]));
        }
        float ta = __fadd_rn(__fadd_rn(r[0], r[1]), __fadd_rn(r[2], r[3]));
        float tb = __fadd_rn(__fadd_rn(r[4], r[5]), __fadd_rn(r[6], r[7]));
        half[h] = __fadd_rn(ta, tb);
    }
    return __fadd_rn(half[0], half[1]);
}

__device__ __forceinline__ bool lex_lt(float s1, int k1, float s2, int k2) {
    return (s1 < s2) || (s1 == s2 && k1 < k2);
}

// merge sorted pair (a1,ka1)<=(a2,ka2) with sorted pair (b1,kb1)<=(b2,kb2); keep 2 smallest
__device__ __forceinline__ void top2_merge(float& a1, int& ka1, float& a2, int& ka2,
                                           float b1, int kb1, float b2, int kb2) {
    if (lex_lt(b1, kb1, a1, ka1)) {
        float t1 = a1; int tk1 = ka1;
        a1 = b1; ka1 = kb1;
        if (lex_lt(b2, kb2, t1, tk1)) { a2 = b2; ka2 = kb2; }
        else                          { a2 = t1; ka2 = tk1; }
    } else {
        if (lex_lt(b1, kb1, a2, ka2)) { a2 = b1; ka2 = kb1; }
    }
}

// ---- kernel 1: emb prep: e2 (np-exact) + e16 = [e_hi(c)|e_lo(c)] fp16, e scaled by 1024 ----
__global__ void __launch_bounds__(256)
prep_emb_kernel(const float* __restrict__ emb, float* __restrict__ e2, f16* __restrict__ e16) {
    int k = blockIdx.x * 256 + threadIdx.x;
    if (k >= KCODES) return;
    const float* er = emb + (size_t)k * CDIM;
    e2[k] = np_sumsq_256(er);
    unsigned int* ph = (unsigned int*)(e16 + (size_t)k * 512);
    unsigned int* pl = (unsigned int*)(e16 + (size_t)k * 512 + 256);
    for (int c = 0; c < 256; c += 2) {
        float s0 = er[c] * 1024.0f, s1 = er[c + 1] * 1024.0f;
        f16 h0 = (f16)s0, h1 = (f16)s1;
        float r0 = __fsub_rn(s0, (float)h0), r1 = __fsub_rn(s1, (float)h1);
        f16 l0 = (f16)r0, l1 = (f16)r1;
        unsigned short uh0 = *(unsigned short*)&h0, uh1 = *(unsigned short*)&h1;
        unsigned short ul0 = *(unsigned short*)&l0, ul1 = *(unsigned short*)&l1;
        ph[c >> 1] = (unsigned int)uh0 | ((unsigned int)uh1 << 16);
        pl[c >> 1] = (unsigned int)ul0 | ((unsigned int)ul1 << 16);
    }
}

// ---- kernel 2: z prep: z2 (np-exact) + A[n][512] = [z_hi|z_lo] fp16, z scaled by 16 ----
__global__ void __launch_bounds__(256)
prep_z_kernel(const float* __restrict__ z, f16* __restrict__ A, float* __restrict__ z2) {
    __shared__ __align__(16) float z_lds[32 * 260];
    const int t = threadIdx.x;
    const int n0 = blockIdx.x * 32;
    const int b = n0 >> 10, hw0 = n0 & 1023;
    const float* zbase = z + (size_t)b * (CDIM * HW) + hw0;
#pragma unroll
    for (int p = 0; p < 8; ++p) {
        int id = p * 256 + t;
        int c = id >> 3;
        int m4 = id & 7;
        float4 v = *(const float4*)(zbase + (size_t)c * HW + m4 * 4);
        z_lds[(m4 * 4 + 0) * 260 + c] = v.x;
        z_lds[(m4 * 4 + 1) * 260 + c] = v.y;
        z_lds[(m4 * 4 + 2) * 260 + c] = v.z;
        z_lds[(m4 * 4 + 3) * 260 + c] = v.w;
    }
    __syncthreads();
    if (t < 32) z2[n0 + t] = np_sumsq_256(&z_lds[t * 260]);

    const int m = t >> 3, cs = (t & 7) * 32;
    const float* zr = &z_lds[m * 260];
    size_t nrow = (size_t)(n0 + m);
    unsigned int* ph = (unsigned int*)(A + nrow * 512 + cs);
    unsigned int* pl = (unsigned int*)(A + nrow * 512 + 256 + cs);
#pragma unroll
    for (int cc = 0; cc < 32; cc += 2) {
        float s0 = zr[cs + cc] * 16.0f, s1 = zr[cs + cc + 1] * 16.0f;
        f16 h0 = (f16)s0, h1 = (f16)s1;
        float r0 = __fsub_rn(s0, (float)h0), r1 = __fsub_rn(s1, (float)h1);
        f16 l0 = (f16)r0, l1 = (f16)r1;
        unsigned short uh0 = *(unsigned short*)&h0, uh1 = *(unsigned short*)&h1;
        unsigned short ul0 = *(unsigned short*)&l0, ul1 = *(unsigned short*)&l1;
        ph[cc >> 1] = (unsigned int)uh0 | ((unsigned int)uh1 << 16);
        pl[cc >> 1] = (unsigned int)ul0 | ((unsigned int)ul1 << 16);
    }
}

// ---- kernel 3: MFMA GEMM (S' = A·B^T, K_eff=1024 via 2 B-phases) + per-row-per-tile top2 ----
// Block 256 thr / 4 waves, tile 128 rows x 128 codes. Grid 2048: Mtile=bid&255 (XCD-affine),
// Ntile=bid>>8. Per wave 64x64 = 4x4 MFMAs of 16x16x32 f16.
// acc = dot' = dot * 2^14 (z scaled 2^4, e scaled 2^10) -> 2*dot = acc * 2^-13.
__global__ void __launch_bounds__(256, 3)
gemm_argmin_kernel(const f16* __restrict__ A, const f16* __restrict__ B,
                   const float* __restrict__ z2, const float* __restrict__ e2,
                   float4* __restrict__ tile_red) {
    __shared__ __align__(16) f16 a_lds[128 * 32];   // 8 KB
    __shared__ __align__(16) f16 b_lds[128 * 32];   // 8 KB
    __shared__ __align__(16) float4 red_lds[4 * 64]; // 4 KB

    const int t = threadIdx.x;
    const int lane = t & 63, wave = t >> 6;
    const int Mtile = blockIdx.x & 255, Ntile = blockIdx.x >> 8;
    const int wm = (wave >> 1) * 64, wn = (wave & 1) * 64;
    const int l15 = lane & 15, quad = lane >> 4;

    const int srow = t >> 2, sseg = t & 3;   // staging: rows q*64+srow, 16B seg sseg

    f32x4 acc[4][4] = {};

    const f16* Abase = A + (size_t)Mtile * 128 * 512;
    const f16* Bbase = B + (size_t)Ntile * 128 * 512;

    float4 av[2], bv[2];
#pragma unroll
    for (int q = 0; q < 2; ++q) {
        av[q] = *(const float4*)(Abase + (size_t)(q * 64 + srow) * 512 + sseg * 8);
        bv[q] = *(const float4*)(Bbase + (size_t)(q * 64 + srow) * 512 + sseg * 8);
    }

    for (int kk = 0; kk < 32; ++kk) {
        __syncthreads();   // readers of previous chunk done
#pragma unroll
        for (int q = 0; q < 2; ++q) {
            *(float4*)&a_lds[(q * 64 + srow) * 32 + sseg * 8] = av[q];
            *(float4*)&b_lds[(q * 64 + srow) * 32 + sseg * 8] = bv[q];
        }
        if (kk < 31) {
            const int kn = kk + 1;
            const int c0 = (kn & 15) * 32;
            const int bc0 = (kn >> 4) ? (c0 ^ 256) : c0;
#pragma unroll
            for (int q = 0; q < 2; ++q) {
                av[q] = *(const float4*)(Abase + (size_t)(q * 64 + srow) * 512 + c0 + sseg * 8);
                bv[q] = *(const float4*)(Bbase + (size_t)(q * 64 + srow) * 512 + bc0 + sseg * 8);
            }
        }
        __syncthreads();   // chunk visible

        f16x8 af[4], bf[4];
#pragma unroll
        for (int i = 0; i < 4; ++i)
            af[i] = *(const f16x8*)&a_lds[(wm + i * 16 + l15) * 32 + quad * 8];
#pragma unroll
        for (int j = 0; j < 4; ++j)
            bf[j] = *(const f16x8*)&b_lds[(wn + j * 16 + l15) * 32 + quad * 8];
#pragma unroll
        for (int i = 0; i < 4; ++i)
#pragma unroll
            for (int j = 0; j < 4; ++j)
                acc[i][j] = __builtin_amdgcn_mfma_f32_16x16x32_f16(af[i], bf[j], acc[i][j], 0, 0, 0);
    }

    // ---- epilogue: d = fl(fl(z2+e2) - fl(acc*2^-13)); per-(i,r) top2 over this block's codes ----
    float e2v[4];
#pragma unroll
    for (int j = 0; j < 4; ++j) e2v[j] = e2[Ntile * 128 + wn + j * 16 + l15];

    float S1[4][4], S2[4][4];
    int   K1v[4][4], K2v[4][4];
#pragma unroll
    for (int i = 0; i < 4; ++i) {
        float z2q[4];
#pragma unroll
        for (int r = 0; r < 4; ++r)
            z2q[r] = z2[Mtile * 128 + wm + i * 16 + quad * 4 + r];
#pragma unroll
        for (int r = 0; r < 4; ++r) {
            float s1 = FLT_BIG, s2 = FLT_BIG;
            int k1 = KCODES, k2 = KCODES;
#pragma unroll
            for (int j = 0; j < 4; ++j) {
                float d = __fsub_rn(__fadd_rn(z2q[r], e2v[j]),
                                    __fmul_rn(acc[i][j][r], 1.220703125e-4f));
                int kc = Ntile * 128 + wn + j * 16 + l15;
                if (lex_lt(d, kc, s1, k1)) { s2 = s1; k2 = k1; s1 = d; k1 = kc; }
                else if (lex_lt(d, kc, s2, k2)) { s2 = d; k2 = kc; }
            }
            S1[i][r] = s1; K1v[i][r] = k1; S2[i][r] = s2; K2v[i][r] = k2;
        }
    }

    // cross-lane merge over the 16 code-lanes (bits 0..3 of lane)
#pragma unroll
    for (int mask = 1; mask <= 8; mask <<= 1) {
#pragma unroll
        for (int i = 0; i < 4; ++i)
#pragma unroll
            for (int r = 0; r < 4; ++r) {
                float b1 = __shfl_xor(S1[i][r], mask);
                int  kb1 = __shfl_xor(K1v[i][r], mask);
                float b2 = __shfl_xor(S2[i][r], mask);
                int  kb2 = __shfl_xor(K2v[i][r], mask);
                top2_merge(S1[i][r], K1v[i][r], S2[i][r], K2v[i][r], b1, kb1, b2, kb2);
            }
    }

    if (l15 == 0) {
#pragma unroll
        for (int i = 0; i < 4; ++i)
#pragma unroll
            for (int r = 0; r < 4; ++r) {
                float4 st;
                st.x = S1[i][r]; st.y = __int_as_float(K1v[i][r]);
                st.z = S2[i][r]; st.w = __int_as_float(K2v[i][r]);
                red_lds[wave * 64 + i * 16 + quad * 4 + r] = st;
            }
    }
    __syncthreads();
    if (t < 128) {
        int wA = (t >> 6) * 2, rw = t & 63;
        float4 a = red_lds[wA * 64 + rw];
        float4 b = red_lds[(wA + 1) * 64 + rw];
        float a1 = a.x, a2 = a.z; int ka1 = __float_as_int(a.y), ka2 = __float_as_int(a.w);
        top2_merge(a1, ka1, a2, ka2, b.x, __float_as_int(b.y), b.z, __float_as_int(b.w));
        float4 o;
        o.x = a1; o.y = __int_as_float(ka1); o.z = a2; o.w = __int_as_float(ka2);
        tile_red[(size_t)(Mtile * 128 + t) * 8 + Ntile] = o;
    }
}

// ---- kernel 4: candidate reduce + exact fp32 rescore (same fmaf chain as rounds 1-3) ----
__global__ void __launch_bounds__(256)
rescore_kernel(const float* __restrict__ z, const float* __restrict__ emb,
               const float* __restrict__ z2, const float* __restrict__ e2,
               const float4* __restrict__ tile_red, float* __restrict__ out_idx_f,
               int* __restrict__ ws_idx) {
    const int n = blockIdx.x * 256 + threadIdx.x;
    float s[16]; int k[16];
#pragma unroll
    for (int i = 0; i < 8; ++i) {
        float4 v = tile_red[(size_t)n * 8 + i];
        s[2 * i] = v.x;     k[2 * i] = __float_as_int(v.y);
        s[2 * i + 1] = v.z; k[2 * i + 1] = __float_as_int(v.w);
    }
    float s1 = FLT_BIG; int k1 = KCODES;
#pragma unroll
    for (int i = 0; i < 16; ++i)
        if (lex_lt(s[i], k[i], s1, k1)) { s1 = s[i]; k1 = k[i]; }
    const float thr = s1 + 2.5e-4f;   // >= 4 ulp at d~512; approx error <= 1 ulp
    int cnt = 0;
#pragma unroll
    for (int i = 0; i < 16; ++i) cnt += (s[i] <= thr) ? 1 : 0;

    int bk = k1;
    if (cnt > 1) {
        int kk[16];
#pragma unroll
        for (int i = 0; i < 16; ++i) kk[i] = (s[i] <= thr) ? k[i] : k1;
        float accs[16];
#pragma unroll
        for (int j = 0; j < 16; ++j) accs[j] = 0.f;
        const float* zb = z + (size_t)(n >> 10) * (CDIM * HW) + (n & 1023);
        for (int c = 0; c < 256; ++c) {
            float zc = zb[(size_t)c * HW];
#pragma unroll
            for (int j = 0; j < 16; ++j)
                accs[j] = fmaf(zc, emb[(size_t)kk[j] * CDIM + c], accs[j]);
        }
        float bd = FLT_BIG; bk = KCODES;
        const float z2n = z2[n];
#pragma unroll
        for (int j = 0; j < 16; ++j) {
            float d = __fsub_rn(__fadd_rn(z2n, e2[kk[j]]), accs[j] + accs[j]);
            if (lex_lt(d, kk[j], bd, bk)) { bd = d; bk = kk[j]; }
        }
    }
    out_idx_f[n] = (float)bk;
    ws_idx[n] = bk;
}

// ---- kernel 5: gather z_q, write z_q_st, partial loss sums (round-2/3 proven) ----
__global__ void __launch_bounds__(256)
gather_kernel(const float* __restrict__ z, const float* __restrict__ emb,
              const int* __restrict__ ws_idx, float* __restrict__ out_zq,
              float* __restrict__ partials) {
    const int t = threadIdx.x;
    const int b = blockIdx.x >> 5;
    const int cg = blockIdx.x & 31;
    const int hw4 = t * 4;

    const int4 iv = *(const int4*)&ws_idx[b * HW + hw4];
    const float* zb = z + (size_t)b * (CDIM * HW) + hw4;
    float* ob = out_zq + (size_t)b * (CDIM * HW) + hw4;
    const float* e0p = emb + (size_t)iv.x * CDIM;
    const float* e1p = emb + (size_t)iv.y * CDIM;
    const float* e2p = emb + (size_t)iv.z * CDIM;
    const float* e3p = emb + (size_t)iv.w * CDIM;

    float lsum = 0.f;
#pragma unroll
    for (int c = cg * 8; c < cg * 8 + 8; ++c) {
        float4 zv = *(const float4*)&zb[(size_t)c * HW];
        float d0 = e0p[c] - zv.x;
        float d1 = e1p[c] - zv.y;
        float d2 = e2p[c] - zv.z;
        float d3 = e3p[c] - zv.w;
        float4 ov = { zv.x + d0, zv.y + d1, zv.z + d2, zv.w + d3 };
        *(float4*)&ob[(size_t)c * HW] = ov;
        lsum = fmaf(d0, d0, lsum);
        lsum = fmaf(d1, d1, lsum);
        lsum = fmaf(d2, d2, lsum);
        lsum = fmaf(d3, d3, lsum);
    }
#pragma unroll
    for (int off = 32; off > 0; off >>= 1) lsum += __shfl_down(lsum, off);
    __shared__ float wsum[4];
    if ((t & 63) == 0) wsum[t >> 6] = lsum;
    __syncthreads();
    if (t == 0) partials[blockIdx.x] = (wsum[0] + wsum[1]) + (wsum[2] + wsum[3]);
}

// ---- kernel 6: finalize loss = 1.25 * mean(diff^2) over 1024 partials ----
__global__ void loss_kernel(const float* __restrict__ partials, float* __restrict__ out_loss) {
    const int t = threadIdx.x;
    float4 v4 = *(const float4*)&partials[t * 4];
    float v = (v4.x + v4.y) + (v4.z + v4.w);
#pragma unroll
    for (int off = 32; off > 0; off >>= 1) v += __shfl_down(v, off);
    __shared__ float wsum[4];
    if ((t & 63) == 0) wsum[t >> 6] = v;
    __syncthreads();
    if (t == 0) {
        float total = (wsum[0] + wsum[1]) + (wsum[2] + wsum[3]);
        out_loss[0] = 1.25f * total / 8388608.0f;
    }
}

extern "C" void kernel_launch(void* const* d_in, const int* in_sizes, int n_in,
                              void* d_out, int out_size, void* d_ws, size_t ws_size,
                              hipStream_t stream) {
    const float* z   = (const float*)d_in[0];
    const float* emb = (const float*)d_in[1];
    float* out = (float*)d_out;

    // A (fp16 [32768][512] = 32 MB) lives in the zq region of d_out; gather overwrites it last.
    f16* A = (f16*)d_out;

    // ws layout (~5.3 MB total)
    char* w = (char*)d_ws;
    float*  e2       = (float*)(w + 0);            // 4 KB
    float*  z2       = (float*)(w + 4096);         // 128 KB
    f16*    e16      = (f16*)(w + 135168);         // 1 MB
    float4* tile_red = (float4*)(w + 1183744);     // 4 MB
    int*    ws_idx   = (int*)(w + 5378048);        // 128 KB
    float*  partials = (float*)(w + 5509120);      // 4 KB

    hipLaunchKernelGGL(prep_emb_kernel, dim3(4), dim3(256), 0, stream, emb, e2, e16);
    hipLaunchKernelGGL(prep_z_kernel, dim3(1024), dim3(256), 0, stream, z, A, z2);
    hipLaunchKernelGGL(gemm_argmin_kernel, dim3(2048), dim3(256), 0, stream,
                       A, e16, z2, e2, tile_red);
    hipLaunchKernelGGL(rescore_kernel, dim3(128), dim3(256), 0, stream,
                       z, emb, z2, e2, tile_red, out + IDX_OFF, ws_idx);
    hipLaunchKernelGGL(gather_kernel, dim3(1024), dim3(256), 0, stream,
                       z, emb, ws_idx, out, partials);
    hipLaunchKernelGGL(loss_kernel, dim3(1), dim3(256), 0, stream,
                       partials, out + LOSS_OFF);
}

// Round 5
// 598.598 us; speedup vs baseline: 1.1815x; 1.1252x over previous
//
#include <hip/hip_runtime.h>

#define CDIM 256
#define HW 1024            // 32*32
#define NROWS 32768        // 32*1024
#define KCODES 1024
#define ZQ_ELEMS 8388608   // 32*256*1024
#define IDX_OFF ZQ_ELEMS
#define LOSS_OFF (ZQ_ELEMS + NROWS)
#define FLT_BIG 3.402823466e+38f

typedef _Float16 f16;
typedef _Float16 f16x8 __attribute__((ext_vector_type(8)));
typedef float f32x4 __attribute__((ext_vector_type(4)));

__device__ __forceinline__ unsigned int pack_f16x2(f16 a, f16 b) {
    unsigned short ua = *(unsigned short*)&a, ub = *(unsigned short*)&b;
    return (unsigned int)ua | ((unsigned int)ub << 16);
}

// ---- numpy-bit-exact pairwise sum of squares over 256 contiguous floats ----
__device__ __forceinline__ float np_sumsq_256(const float* __restrict__ a) {
    float half[2];
#pragma unroll
    for (int h = 0; h < 2; ++h) {
        const float* p = a + h * 128;
        float r[8];
#pragma unroll
        for (int j = 0; j < 8; ++j) r[j] = __fmul_rn(p[j], p[j]);
#pragma unroll
        for (int i = 8; i < 128; i += 8) {
#pragma unroll
            for (int j = 0; j < 8; ++j)
                r[j] = __fadd_rn(r[j], __fmul_rn(p[i + j], p[i + j]));
        }
        float ta = __fadd_rn(__fadd_rn(r[0], r[1]), __fadd_rn(r[2], r[3]));
        float tb = __fadd_rn(__fadd_rn(r[4], r[5]), __fadd_rn(r[6], r[7]));
        half[h] = __fadd_rn(ta, tb);
    }
    return __fadd_rn(half[0], half[1]);
}

__device__ __forceinline__ bool lex_lt(float s1, int k1, float s2, int k2) {
    return (s1 < s2) || (s1 == s2 && k1 < k2);
}

__device__ __forceinline__ void top2_merge(float& a1, int& ka1, float& a2, int& ka2,
                                           float b1, int kb1, float b2, int kb2) {
    if (lex_lt(b1, kb1, a1, ka1)) {
        float t1 = a1; int tk1 = ka1;
        a1 = b1; ka1 = kb1;
        if (lex_lt(b2, kb2, t1, tk1)) { a2 = b2; ka2 = kb2; }
        else                          { a2 = t1; ka2 = tk1; }
    } else {
        if (lex_lt(b1, kb1, a2, ka2)) { a2 = b1; ka2 = kb1; }
    }
}

// ---- kernel 1a: e2[k] = np-exact sum(emb[k,:]**2) ----
__global__ void __launch_bounds__(256)
e2_kernel(const float* __restrict__ emb, float* __restrict__ e2) {
    int k = blockIdx.x * 256 + threadIdx.x;
    if (k >= KCODES) return;
    e2[k] = np_sumsq_256(emb + (size_t)k * CDIM);
}

// ---- kernel 1b: e16[k] = [e_hi | e_lo] fp16, e scaled by 1024 (parallel, coalesced) ----
__global__ void __launch_bounds__(256)
econv_kernel(const float* __restrict__ emb, f16* __restrict__ e16) {
    const int gid = blockIdx.x * 256 + threadIdx.x;   // 0..32767
    const int k = gid >> 5, seg = gid & 31;           // seg covers 8 c
    const float* src = emb + (size_t)k * CDIM + seg * 8;
    float4 v0 = *(const float4*)src;
    float4 v1 = *(const float4*)(src + 4);
    float s[8] = { v0.x, v0.y, v0.z, v0.w, v1.x, v1.y, v1.z, v1.w };
    f16 h[8], l[8];
#pragma unroll
    for (int j = 0; j < 8; ++j) {
        float sv = s[j] * 1024.0f;
        h[j] = (f16)sv;
        float r = __fsub_rn(sv, (float)h[j]);
        l[j] = (f16)r;
    }
    uint4 hv, lv;
    hv.x = pack_f16x2(h[0], h[1]); hv.y = pack_f16x2(h[2], h[3]);
    hv.z = pack_f16x2(h[4], h[5]); hv.w = pack_f16x2(h[6], h[7]);
    lv.x = pack_f16x2(l[0], l[1]); lv.y = pack_f16x2(l[2], l[3]);
    lv.z = pack_f16x2(l[4], l[5]); lv.w = pack_f16x2(l[6], l[7]);
    *(uint4*)(e16 + (size_t)k * 512 + seg * 8) = hv;
    *(uint4*)(e16 + (size_t)k * 512 + 256 + seg * 8) = lv;
}

// ---- kernel 2: z prep: z2 (np-exact) + A[n][512] = [z_hi|z_lo] fp16, z scaled by 16 ----
// wave stores 1 KB contiguous per row: lanes 0-31 = hi segs, 32-63 = lo segs.
__global__ void __launch_bounds__(256)
prep_z_kernel(const float* __restrict__ z, f16* __restrict__ A, float* __restrict__ z2) {
    __shared__ __align__(16) float z_lds[32 * 260];
    const int t = threadIdx.x;
    const int n0 = blockIdx.x * 32;
    const int b = n0 >> 10, hw0 = n0 & 1023;
    const float* zbase = z + (size_t)b * (CDIM * HW) + hw0;
#pragma unroll
    for (int p = 0; p < 8; ++p) {
        int id = p * 256 + t;
        int c = id >> 3;
        int m4 = id & 7;
        float4 v = *(const float4*)(zbase + (size_t)c * HW + m4 * 4);
        z_lds[(m4 * 4 + 0) * 260 + c] = v.x;
        z_lds[(m4 * 4 + 1) * 260 + c] = v.y;
        z_lds[(m4 * 4 + 2) * 260 + c] = v.z;
        z_lds[(m4 * 4 + 3) * 260 + c] = v.w;
    }
    __syncthreads();
    if (t < 32) z2[n0 + t] = np_sumsq_256(&z_lds[t * 260]);

    const int lane = t & 63, wave = t >> 6;
    const int half = lane >> 5;       // 0 = hi, 1 = lo
    const int seg = lane & 31;        // 8 c per seg
#pragma unroll
    for (int rr = 0; rr < 8; ++rr) {
        const int m = wave * 8 + rr;
        const float* zr = &z_lds[m * 260 + seg * 8];
        f16 o[8];
#pragma unroll
        for (int j = 0; j < 8; ++j) {
            float sv = zr[j] * 16.0f;
            f16 hh = (f16)sv;
            if (half) {
                float r = __fsub_rn(sv, (float)hh);
                o[j] = (f16)r;
            } else {
                o[j] = hh;
            }
        }
        uint4 ov;
        ov.x = pack_f16x2(o[0], o[1]); ov.y = pack_f16x2(o[2], o[3]);
        ov.z = pack_f16x2(o[4], o[5]); ov.w = pack_f16x2(o[6], o[7]);
        *(uint4*)(A + (size_t)(n0 + m) * 512 + half * 256 + seg * 8) = ov;
    }
}

// ---- kernel 3: MFMA GEMM + per-row-per-tile top2 ----
// Block 256 thr / 4 waves, tile 128 rows x 128 codes. Grid 2048:
// Ntile = bid&7 (XCD-pinned B tile), Mtile = bid>>3.
// K-loop: 16 iters of BK=32; per iter stage A chunk + B phase-1 chunk + B
// phase-2 chunk (bytes ^512), 1 barrier/iter, register double-buffer prefetch.
// acc = dot * 2^14 (z scaled 2^4, e scaled 2^10) -> 2*dot = acc * 2^-13.
__global__ void __launch_bounds__(256, 3)
gemm_argmin_kernel(const f16* __restrict__ A, const f16* __restrict__ B,
                   const float* __restrict__ z2, const float* __restrict__ e2,
                   float4* __restrict__ tile_red) {
    __shared__ __align__(16) f16 a_lds[2][128 * 32];    // 2 x 8 KB
    __shared__ __align__(16) f16 b1_lds[2][128 * 32];   // 2 x 8 KB
    __shared__ __align__(16) f16 b2_lds[2][128 * 32];   // 2 x 8 KB
    __shared__ __align__(16) float4 red_lds[4 * 64];    // 4 KB

    const int t = threadIdx.x;
    const int lane = t & 63, wave = t >> 6;
    const int Ntile = blockIdx.x & 7, Mtile = blockIdx.x >> 3;
    const int wm = (wave >> 1) * 64, wn = (wave & 1) * 64;
    const int l15 = lane & 15, quad = lane >> 4;

    // staging: thread covers bytes [t*32, t*32+32) of each 8 KB chunk
    const char* ag = (const char*)(A + (size_t)Mtile * 128 * 512)
                     + (size_t)(t >> 1) * 1024 + (t & 1) * 32;
    const char* bg = (const char*)(B + (size_t)Ntile * 128 * 512)
                     + (size_t)(t >> 1) * 1024 + (t & 1) * 32;

    f32x4 acc[4][4] = {};

    float4 av[2], b1v[2], b2v[2];
    av[0]  = *(const float4*)(ag);        av[1]  = *(const float4*)(ag + 16);
    b1v[0] = *(const float4*)(bg);        b1v[1] = *(const float4*)(bg + 16);
    b2v[0] = *(const float4*)(bg + 512);  b2v[1] = *(const float4*)(bg + 528);

    for (int kk = 0; kk < 16; ++kk) {
        const int buf = kk & 1;
        char* al  = (char*)a_lds[buf]  + t * 32;
        char* b1l = (char*)b1_lds[buf] + t * 32;
        char* b2l = (char*)b2_lds[buf] + t * 32;
        *(float4*)(al)       = av[0];  *(float4*)(al + 16)  = av[1];
        *(float4*)(b1l)      = b1v[0]; *(float4*)(b1l + 16) = b1v[1];
        *(float4*)(b2l)      = b2v[0]; *(float4*)(b2l + 16) = b2v[1];

        if (kk < 15) {
            const int ko = (kk + 1) * 64;        // byte offset in 1024-B row
            const int ko2 = ko ^ 512;
            av[0]  = *(const float4*)(ag + ko);        av[1]  = *(const float4*)(ag + ko + 16);
            b1v[0] = *(const float4*)(bg + ko);        b1v[1] = *(const float4*)(bg + ko + 16);
            b2v[0] = *(const float4*)(bg + ko2);       b2v[1] = *(const float4*)(bg + ko2 + 16);
        }
        __syncthreads();   // buf visible; prefetch stays in flight during compute

        f16x8 af[4], bf1[4], bf2[4];
#pragma unroll
        for (int i = 0; i < 4; ++i)
            af[i] = *(const f16x8*)&a_lds[buf][(wm + i * 16 + l15) * 32 + quad * 8];
#pragma unroll
        for (int j = 0; j < 4; ++j) {
            bf1[j] = *(const f16x8*)&b1_lds[buf][(wn + j * 16 + l15) * 32 + quad * 8];
            bf2[j] = *(const f16x8*)&b2_lds[buf][(wn + j * 16 + l15) * 32 + quad * 8];
        }
#pragma unroll
        for (int i = 0; i < 4; ++i)
#pragma unroll
            for (int j = 0; j < 4; ++j) {
                acc[i][j] = __builtin_amdgcn_mfma_f32_16x16x32_f16(af[i], bf1[j], acc[i][j], 0, 0, 0);
                acc[i][j] = __builtin_amdgcn_mfma_f32_16x16x32_f16(af[i], bf2[j], acc[i][j], 0, 0, 0);
            }
    }

    // ---- epilogue: d = fl(fl(z2+e2) - fl(acc*2^-13)); per-(i,r) top2 ----
    float e2v[4];
#pragma unroll
    for (int j = 0; j < 4; ++j) e2v[j] = e2[Ntile * 128 + wn + j * 16 + l15];

    float S1[4][4], S2[4][4];
    int   K1v[4][4], K2v[4][4];
#pragma unroll
    for (int i = 0; i < 4; ++i) {
        float z2q[4];
#pragma unroll
        for (int r = 0; r < 4; ++r)
            z2q[r] = z2[Mtile * 128 + wm + i * 16 + quad * 4 + r];
#pragma unroll
        for (int r = 0; r < 4; ++r) {
            float s1 = FLT_BIG, s2 = FLT_BIG;
            int k1 = KCODES, k2 = KCODES;
#pragma unroll
            for (int j = 0; j < 4; ++j) {
                float d = __fsub_rn(__fadd_rn(z2q[r], e2v[j]),
                                    __fmul_rn(acc[i][j][r], 1.220703125e-4f));
                int kc = Ntile * 128 + wn + j * 16 + l15;
                if (lex_lt(d, kc, s1, k1)) { s2 = s1; k2 = k1; s1 = d; k1 = kc; }
                else if (lex_lt(d, kc, s2, k2)) { s2 = d; k2 = kc; }
            }
            S1[i][r] = s1; K1v[i][r] = k1; S2[i][r] = s2; K2v[i][r] = k2;
        }
    }

#pragma unroll
    for (int mask = 1; mask <= 8; mask <<= 1) {
#pragma unroll
        for (int i = 0; i < 4; ++i)
#pragma unroll
            for (int r = 0; r < 4; ++r) {
                float b1 = __shfl_xor(S1[i][r], mask);
                int  kb1 = __shfl_xor(K1v[i][r], mask);
                float b2 = __shfl_xor(S2[i][r], mask);
                int  kb2 = __shfl_xor(K2v[i][r], mask);
                top2_merge(S1[i][r], K1v[i][r], S2[i][r], K2v[i][r], b1, kb1, b2, kb2);
            }
    }

    if (l15 == 0) {
#pragma unroll
        for (int i = 0; i < 4; ++i)
#pragma unroll
            for (int r = 0; r < 4; ++r) {
                float4 st;
                st.x = S1[i][r]; st.y = __int_as_float(K1v[i][r]);
                st.z = S2[i][r]; st.w = __int_as_float(K2v[i][r]);
                red_lds[wave * 64 + i * 16 + quad * 4 + r] = st;
            }
    }
    __syncthreads();
    if (t < 128) {
        int wA = (t >> 6) * 2, rw = t & 63;
        float4 a = red_lds[wA * 64 + rw];
        float4 b = red_lds[(wA + 1) * 64 + rw];
        float a1 = a.x, a2 = a.z; int ka1 = __float_as_int(a.y), ka2 = __float_as_int(a.w);
        top2_merge(a1, ka1, a2, ka2, b.x, __float_as_int(b.y), b.z, __float_as_int(b.w));
        float4 o;
        o.x = a1; o.y = __int_as_float(ka1); o.z = a2; o.w = __int_as_float(ka2);
        tile_red[(size_t)(Mtile * 128 + t) * 8 + Ntile] = o;
    }
}

// ---- kernel 4: candidate reduce + exact fp32 rescore (verified round 4) ----
__global__ void __launch_bounds__(256)
rescore_kernel(const float* __restrict__ z, const float* __restrict__ emb,
               const float* __restrict__ z2, const float* __restrict__ e2,
               const float4* __restrict__ tile_red, float* __restrict__ out_idx_f,
               int* __restrict__ ws_idx) {
    const int n = blockIdx.x * 256 + threadIdx.x;
    float s[16]; int k[16];
#pragma unroll
    for (int i = 0; i < 8; ++i) {
        float4 v = tile_red[(size_t)n * 8 + i];
        s[2 * i] = v.x;     k[2 * i] = __float_as_int(v.y);
        s[2 * i + 1] = v.z; k[2 * i + 1] = __float_as_int(v.w);
    }
    float s1 = FLT_BIG; int k1 = KCODES;
#pragma unroll
    for (int i = 0; i < 16; ++i)
        if (lex_lt(s[i], k[i], s1, k1)) { s1 = s[i]; k1 = k[i]; }
    const float thr = s1 + 2.5e-4f;
    int cnt = 0;
#pragma unroll
    for (int i = 0; i < 16; ++i) cnt += (s[i] <= thr) ? 1 : 0;

    int bk = k1;
    if (cnt > 1) {
        int kk[16];
#pragma unroll
        for (int i = 0; i < 16; ++i) kk[i] = (s[i] <= thr) ? k[i] : k1;
        float accs[16];
#pragma unroll
        for (int j = 0; j < 16; ++j) accs[j] = 0.f;
        const float* zb = z + (size_t)(n >> 10) * (CDIM * HW) + (n & 1023);
        for (int c = 0; c < 256; ++c) {
            float zc = zb[(size_t)c * HW];
#pragma unroll
            for (int j = 0; j < 16; ++j)
                accs[j] = fmaf(zc, emb[(size_t)kk[j] * CDIM + c], accs[j]);
        }
        float bd = FLT_BIG; bk = KCODES;
        const float z2n = z2[n];
#pragma unroll
        for (int j = 0; j < 16; ++j) {
            float d = __fsub_rn(__fadd_rn(z2n, e2[kk[j]]), accs[j] + accs[j]);
            if (lex_lt(d, kk[j], bd, bk)) { bd = d; bk = kk[j]; }
        }
    }
    out_idx_f[n] = (float)bk;
    ws_idx[n] = bk;
}

// ---- kernel 5: gather z_q, write z_q_st, partial loss sums ----
__global__ void __launch_bounds__(256)
gather_kernel(const float* __restrict__ z, const float* __restrict__ emb,
              const int* __restrict__ ws_idx, float* __restrict__ out_zq,
              float* __restrict__ partials) {
    const int t = threadIdx.x;
    const int b = blockIdx.x >> 5;
    const int cg = blockIdx.x & 31;
    const int hw4 = t * 4;

    const int4 iv = *(const int4*)&ws_idx[b * HW + hw4];
    const float* zb = z + (size_t)b * (CDIM * HW) + hw4;
    float* ob = out_zq + (size_t)b * (CDIM * HW) + hw4;
    const float* e0p = emb + (size_t)iv.x * CDIM;
    const float* e1p = emb + (size_t)iv.y * CDIM;
    const float* e2p = emb + (size_t)iv.z * CDIM;
    const float* e3p = emb + (size_t)iv.w * CDIM;

    float lsum = 0.f;
#pragma unroll
    for (int c = cg * 8; c < cg * 8 + 8; ++c) {
        float4 zv = *(const float4*)&zb[(size_t)c * HW];
        float d0 = e0p[c] - zv.x;
        float d1 = e1p[c] - zv.y;
        float d2 = e2p[c] - zv.z;
        float d3 = e3p[c] - zv.w;
        float4 ov = { zv.x + d0, zv.y + d1, zv.z + d2, zv.w + d3 };
        *(float4*)&ob[(size_t)c * HW] = ov;
        lsum = fmaf(d0, d0, lsum);
        lsum = fmaf(d1, d1, lsum);
        lsum = fmaf(d2, d2, lsum);
        lsum = fmaf(d3, d3, lsum);
    }
#pragma unroll
    for (int off = 32; off > 0; off >>= 1) lsum += __shfl_down(lsum, off);
    __shared__ float wsum[4];
    if ((t & 63) == 0) wsum[t >> 6] = lsum;
    __syncthreads();
    if (t == 0) partials[blockIdx.x] = (wsum[0] + wsum[1]) + (wsum[2] + wsum[3]);
}

// ---- kernel 6: finalize loss = 1.25 * mean(diff^2) over 1024 partials ----
__global__ void loss_kernel(const float* __restrict__ partials, float* __restrict__ out_loss) {
    const int t = threadIdx.x;
    float4 v4 = *(const float4*)&partials[t * 4];
    float v = (v4.x + v4.y) + (v4.z + v4.w);
#pragma unroll
    for (int off = 32; off > 0; off >>= 1) v += __shfl_down(v, off);
    __shared__ float wsum[4];
    if ((t & 63) == 0) wsum[t >> 6] = v;
    __syncthreads();
    if (t == 0) {
        float total = (wsum[0] + wsum[1]) + (wsum[2] + wsum[3]);
        out_loss[0] = 1.25f * total / 8388608.0f;
    }
}

extern "C" void kernel_launch(void* const* d_in, const int* in_sizes, int n_in,
                              void* d_out, int out_size, void* d_ws, size_t ws_size,
                              hipStream_t stream) {
    const float* z   = (const float*)d_in[0];
    const float* emb = (const float*)d_in[1];
    float* out = (float*)d_out;

    // A (fp16 [32768][512] = 32 MB) lives in the zq region of d_out; gather overwrites it last.
    f16* A = (f16*)d_out;

    char* w = (char*)d_ws;
    float*  e2       = (float*)(w + 0);            // 4 KB
    float*  z2       = (float*)(w + 4096);         // 128 KB
    f16*    e16      = (f16*)(w + 135168);         // 1 MB
    float4* tile_red = (float4*)(w + 1183744);     // 4 MB
    int*    ws_idx   = (int*)(w + 5378048);        // 128 KB
    float*  partials = (float*)(w + 5509120);      // 4 KB

    hipLaunchKernelGGL(e2_kernel, dim3(4), dim3(256), 0, stream, emb, e2);
    hipLaunchKernelGGL(econv_kernel, dim3(128), dim3(256), 0, stream, emb, e16);
    hipLaunchKernelGGL(prep_z_kernel, dim3(1024), dim3(256), 0, stream, z, A, z2);
    hipLaunchKernelGGL(gemm_argmin_kernel, dim3(2048), dim3(256), 0, stream,
                       A, e16, z2, e2, tile_red);
    hipLaunchKernelGGL(rescore_kernel, dim3(128), dim3(256), 0, stream,
                       z, emb, z2, e2, tile_red, out + IDX_OFF, ws_idx);
    hipLaunchKernelGGL(gather_kernel, dim3(1024), dim3(256), 0, stream,
                       z, emb, ws_idx, out, partials);
    hipLaunchKernelGGL(loss_kernel, dim3(1), dim3(256), 0, stream,
                       partials, out + LOSS_OFF);
}

// Round 6
// 459.770 us; speedup vs baseline: 1.5383x; 1.3019x over previous
//
#include <hip/hip_runtime.h>

#define CDIM 256
#define HW 1024            // 32*32
#define NROWS 32768        // 32*1024
#define KCODES 1024
#define ZQ_ELEMS 8388608   // 32*256*1024
#define IDX_OFF ZQ_ELEMS
#define LOSS_OFF (ZQ_ELEMS + NROWS)
#define FLT_BIG 3.402823466e+38f

typedef _Float16 f16;
typedef _Float16 f16x8 __attribute__((ext_vector_type(8)));
typedef float f32x4 __attribute__((ext_vector_type(4)));

__device__ __forceinline__ unsigned int pack_f16x2(f16 a, f16 b) {
    unsigned short ua = *(unsigned short*)&a, ub = *(unsigned short*)&b;
    return (unsigned int)ua | ((unsigned int)ub << 16);
}

// ---- numpy-bit-exact pairwise sum of squares over 256 contiguous floats ----
__device__ __forceinline__ float np_sumsq_256(const float* __restrict__ a) {
    float half[2];
#pragma unroll
    for (int h = 0; h < 2; ++h) {
        const float* p = a + h * 128;
        float r[8];
#pragma unroll
        for (int j = 0; j < 8; ++j) r[j] = __fmul_rn(p[j], p[j]);
#pragma unroll
        for (int i = 8; i < 128; i += 8) {
#pragma unroll
            for (int j = 0; j < 8; ++j)
                r[j] = __fadd_rn(r[j], __fmul_rn(p[i + j], p[i + j]));
        }
        float ta = __fadd_rn(__fadd_rn(r[0], r[1]), __fadd_rn(r[2], r[3]));
        float tb = __fadd_rn(__fadd_rn(r[4], r[5]), __fadd_rn(r[6], r[7]));
        half[h] = __fadd_rn(ta, tb);
    }
    return __fadd_rn(half[0], half[1]);
}

__device__ __forceinline__ bool lex_lt(float s1, int k1, float s2, int k2) {
    return (s1 < s2) || (s1 == s2 && k1 < k2);
}

__device__ __forceinline__ void top2_merge(float& a1, int& ka1, float& a2, int& ka2,
                                           float b1, int kb1, float b2, int kb2) {
    if (lex_lt(b1, kb1, a1, ka1)) {
        float t1 = a1; int tk1 = ka1;
        a1 = b1; ka1 = kb1;
        if (lex_lt(b2, kb2, t1, tk1)) { a2 = b2; ka2 = kb2; }
        else                          { a2 = t1; ka2 = tk1; }
    } else {
        if (lex_lt(b1, kb1, a2, ka2)) { a2 = b1; ka2 = kb1; }
    }
}

// ---- kernel 1: fused emb prep: e16 conversion (all threads) + e2 (seg==0 threads) ----
__global__ void __launch_bounds__(256)
prep_emb_kernel(const float* __restrict__ emb, float* __restrict__ e2, f16* __restrict__ e16) {
    const int gid = blockIdx.x * 256 + threadIdx.x;   // 0..32767
    const int k = gid >> 5, seg = gid & 31;           // seg covers 8 c
    const float* src = emb + (size_t)k * CDIM + seg * 8;
    float4 v0 = *(const float4*)src;
    float4 v1 = *(const float4*)(src + 4);
    float s[8] = { v0.x, v0.y, v0.z, v0.w, v1.x, v1.y, v1.z, v1.w };
    f16 h[8], l[8];
#pragma unroll
    for (int j = 0; j < 8; ++j) {
        float sv = s[j] * 1024.0f;
        h[j] = (f16)sv;
        float r = __fsub_rn(sv, (float)h[j]);
        l[j] = (f16)r;
    }
    uint4 hv, lv;
    hv.x = pack_f16x2(h[0], h[1]); hv.y = pack_f16x2(h[2], h[3]);
    hv.z = pack_f16x2(h[4], h[5]); hv.w = pack_f16x2(h[6], h[7]);
    lv.x = pack_f16x2(l[0], l[1]); lv.y = pack_f16x2(l[2], l[3]);
    lv.z = pack_f16x2(l[4], l[5]); lv.w = pack_f16x2(l[6], l[7]);
    *(uint4*)(e16 + (size_t)k * 512 + seg * 8) = hv;
    *(uint4*)(e16 + (size_t)k * 512 + 256 + seg * 8) = lv;
    if (seg == 0) e2[k] = np_sumsq_256(emb + (size_t)k * CDIM);
}

// ---- kernel 2: z prep: z2 (np-exact) + A[n][512] = [z_hi|z_lo] fp16, z scaled by 16 ----
__global__ void __launch_bounds__(256)
prep_z_kernel(const float* __restrict__ z, f16* __restrict__ A, float* __restrict__ z2) {
    __shared__ __align__(16) float z_lds[32 * 260];
    const int t = threadIdx.x;
    const int n0 = blockIdx.x * 32;
    const int b = n0 >> 10, hw0 = n0 & 1023;
    const float* zbase = z + (size_t)b * (CDIM * HW) + hw0;
#pragma unroll
    for (int p = 0; p < 8; ++p) {
        int id = p * 256 + t;
        int c = id >> 3;
        int m4 = id & 7;
        float4 v = *(const float4*)(zbase + (size_t)c * HW + m4 * 4);
        z_lds[(m4 * 4 + 0) * 260 + c] = v.x;
        z_lds[(m4 * 4 + 1) * 260 + c] = v.y;
        z_lds[(m4 * 4 + 2) * 260 + c] = v.z;
        z_lds[(m4 * 4 + 3) * 260 + c] = v.w;
    }
    __syncthreads();
    if (t < 32) z2[n0 + t] = np_sumsq_256(&z_lds[t * 260]);

    const int lane = t & 63, wave = t >> 6;
    const int half = lane >> 5;       // 0 = hi, 1 = lo
    const int seg = lane & 31;        // 8 c per seg
#pragma unroll
    for (int rr = 0; rr < 8; ++rr) {
        const int m = wave * 8 + rr;
        const float* zr = &z_lds[m * 260 + seg * 8];
        f16 o[8];
#pragma unroll
        for (int j = 0; j < 8; ++j) {
            float sv = zr[j] * 16.0f;
            f16 hh = (f16)sv;
            if (half) {
                float r = __fsub_rn(sv, (float)hh);
                o[j] = (f16)r;
            } else {
                o[j] = hh;
            }
        }
        uint4 ov;
        ov.x = pack_f16x2(o[0], o[1]); ov.y = pack_f16x2(o[2], o[3]);
        ov.z = pack_f16x2(o[4], o[5]); ov.w = pack_f16x2(o[6], o[7]);
        *(uint4*)(A + (size_t)(n0 + m) * 512 + half * 256 + seg * 8) = ov;
    }
}

// ---- kernel 3: MFMA GEMM + per-row-per-tile top2 ----
// Block 256 thr / 4 waves, tile 128 rows x 128 codes. Grid 2048:
// Mtile = bid&255 (same-Mtile blocks land on the same XCD -> A read once,
// L3-resident thereafter), Ntile = bid>>8.
// K-loop: 16 iters of 32 halves; LDS double-buffer, register prefetch,
// 1 barrier/iter. B phase loop halves operand registers (no spill at <=256 cap).
__global__ void __launch_bounds__(256, 2)
gemm_argmin_kernel(const f16* __restrict__ A, const f16* __restrict__ B,
                   const float* __restrict__ z2, const float* __restrict__ e2,
                   float4* __restrict__ tile_red) {
    __shared__ __align__(16) f16 a_lds[2][128 * 32];    // 2 x 8 KB
    __shared__ __align__(16) f16 b1_lds[2][128 * 32];   // 2 x 8 KB
    __shared__ __align__(16) f16 b2_lds[2][128 * 32];   // 2 x 8 KB
    __shared__ __align__(16) float4 red_lds[4 * 64];    // 4 KB

    const int t = threadIdx.x;
    const int lane = t & 63, wave = t >> 6;
    const int Mtile = blockIdx.x & 255, Ntile = blockIdx.x >> 8;
    const int wm = (wave >> 1) * 64, wn = (wave & 1) * 64;
    const int l15 = lane & 15, quad = lane >> 4;

    const char* ag = (const char*)(A + (size_t)Mtile * 128 * 512)
                     + (size_t)(t >> 1) * 1024 + (t & 1) * 32;
    const char* bg = (const char*)(B + (size_t)Ntile * 128 * 512)
                     + (size_t)(t >> 1) * 1024 + (t & 1) * 32;

    f32x4 acc[4][4] = {};

    float4 av[2], b1v[2], b2v[2];
    av[0]  = *(const float4*)(ag);        av[1]  = *(const float4*)(ag + 16);
    b1v[0] = *(const float4*)(bg);        b1v[1] = *(const float4*)(bg + 16);
    b2v[0] = *(const float4*)(bg + 512);  b2v[1] = *(const float4*)(bg + 528);

    for (int kk = 0; kk < 16; ++kk) {
        const int buf = kk & 1;
        char* al  = (char*)a_lds[buf]  + t * 32;
        char* b1l = (char*)b1_lds[buf] + t * 32;
        char* b2l = (char*)b2_lds[buf] + t * 32;
        *(float4*)(al)       = av[0];  *(float4*)(al + 16)  = av[1];
        *(float4*)(b1l)      = b1v[0]; *(float4*)(b1l + 16) = b1v[1];
        *(float4*)(b2l)      = b2v[0]; *(float4*)(b2l + 16) = b2v[1];

        if (kk < 15) {
            const int ko = (kk + 1) * 64;        // byte offset in 1024-B row
            const int ko2 = ko ^ 512;
            av[0]  = *(const float4*)(ag + ko);   av[1]  = *(const float4*)(ag + ko + 16);
            b1v[0] = *(const float4*)(bg + ko);   b1v[1] = *(const float4*)(bg + ko + 16);
            b2v[0] = *(const float4*)(bg + ko2);  b2v[1] = *(const float4*)(bg + ko2 + 16);
        }
        __syncthreads();

        f16x8 af[4];
#pragma unroll
        for (int i = 0; i < 4; ++i)
            af[i] = *(const f16x8*)&a_lds[buf][(wm + i * 16 + l15) * 32 + quad * 8];
#pragma unroll
        for (int ph = 0; ph < 2; ++ph) {
            const f16* bl = ph ? b2_lds[buf] : b1_lds[buf];
            f16x8 bf[4];
#pragma unroll
            for (int j = 0; j < 4; ++j)
                bf[j] = *(const f16x8*)&bl[(wn + j * 16 + l15) * 32 + quad * 8];
#pragma unroll
            for (int i = 0; i < 4; ++i)
#pragma unroll
                for (int j = 0; j < 4; ++j)
                    acc[i][j] = __builtin_amdgcn_mfma_f32_16x16x32_f16(af[i], bf[j], acc[i][j], 0, 0, 0);
        }
    }

    // ---- epilogue: d = fl(fl(z2+e2) - fl(acc*2^-13)); per-(i,r) top2 ----
    float e2v[4];
#pragma unroll
    for (int j = 0; j < 4; ++j) e2v[j] = e2[Ntile * 128 + wn + j * 16 + l15];

    float S1[4][4], S2[4][4];
    int   K1v[4][4], K2v[4][4];
#pragma unroll
    for (int i = 0; i < 4; ++i) {
        float z2q[4];
#pragma unroll
        for (int r = 0; r < 4; ++r)
            z2q[r] = z2[Mtile * 128 + wm + i * 16 + quad * 4 + r];
#pragma unroll
        for (int r = 0; r < 4; ++r) {
            float s1 = FLT_BIG, s2 = FLT_BIG;
            int k1 = KCODES, k2 = KCODES;
#pragma unroll
            for (int j = 0; j < 4; ++j) {
                float d = __fsub_rn(__fadd_rn(z2q[r], e2v[j]),
                                    __fmul_rn(acc[i][j][r], 1.220703125e-4f));
                int kc = Ntile * 128 + wn + j * 16 + l15;
                if (lex_lt(d, kc, s1, k1)) { s2 = s1; k2 = k1; s1 = d; k1 = kc; }
                else if (lex_lt(d, kc, s2, k2)) { s2 = d; k2 = kc; }
            }
            S1[i][r] = s1; K1v[i][r] = k1; S2[i][r] = s2; K2v[i][r] = k2;
        }
    }

#pragma unroll
    for (int mask = 1; mask <= 8; mask <<= 1) {
#pragma unroll
        for (int i = 0; i < 4; ++i)
#pragma unroll
            for (int r = 0; r < 4; ++r) {
                float b1 = __shfl_xor(S1[i][r], mask);
                int  kb1 = __shfl_xor(K1v[i][r], mask);
                float b2 = __shfl_xor(S2[i][r], mask);
                int  kb2 = __shfl_xor(K2v[i][r], mask);
                top2_merge(S1[i][r], K1v[i][r], S2[i][r], K2v[i][r], b1, kb1, b2, kb2);
            }
    }

    if (l15 == 0) {
#pragma unroll
        for (int i = 0; i < 4; ++i)
#pragma unroll
            for (int r = 0; r < 4; ++r) {
                float4 st;
                st.x = S1[i][r]; st.y = __int_as_float(K1v[i][r]);
                st.z = S2[i][r]; st.w = __int_as_float(K2v[i][r]);
                red_lds[wave * 64 + i * 16 + quad * 4 + r] = st;
            }
    }
    __syncthreads();
    if (t < 128) {
        int wA = (t >> 6) * 2, rw = t & 63;
        float4 a = red_lds[wA * 64 + rw];
        float4 b = red_lds[(wA + 1) * 64 + rw];
        float a1 = a.x, a2 = a.z; int ka1 = __float_as_int(a.y), ka2 = __float_as_int(a.w);
        top2_merge(a1, ka1, a2, ka2, b.x, __float_as_int(b.y), b.z, __float_as_int(b.w));
        float4 o;
        o.x = a1; o.y = __int_as_float(ka1); o.z = a2; o.w = __int_as_float(ka2);
        tile_red[(size_t)(Mtile * 128 + t) * 8 + Ntile] = o;
    }
}

// ---- kernel 4: candidate reduce + exact fp32 rescore ----
// margin 1e-4 (error bound |d_approx-d_exact| <= ~1.8e-5; need >=3.6e-5).
// Slow path uses float4 emb loads; fmaf chain per candidate is ascending-c
// sequential — identical to the reference chain.
__global__ void __launch_bounds__(256)
rescore_kernel(const float* __restrict__ z, const float* __restrict__ emb,
               const float* __restrict__ z2, const float* __restrict__ e2,
               const float4* __restrict__ tile_red, float* __restrict__ out_idx_f,
               int* __restrict__ ws_idx) {
    const int n = blockIdx.x * 256 + threadIdx.x;
    float s[16]; int k[16];
#pragma unroll
    for (int i = 0; i < 8; ++i) {
        float4 v = tile_red[(size_t)n * 8 + i];
        s[2 * i] = v.x;     k[2 * i] = __float_as_int(v.y);
        s[2 * i + 1] = v.z; k[2 * i + 1] = __float_as_int(v.w);
    }
    float s1 = FLT_BIG; int k1 = KCODES;
#pragma unroll
    for (int i = 0; i < 16; ++i)
        if (lex_lt(s[i], k[i], s1, k1)) { s1 = s[i]; k1 = k[i]; }
    const float thr = s1 + 1.0e-4f;
    int cnt = 0;
#pragma unroll
    for (int i = 0; i < 16; ++i) cnt += (s[i] <= thr) ? 1 : 0;

    int bk = k1;
    if (cnt > 1) {
        int kk[16];
#pragma unroll
        for (int i = 0; i < 16; ++i) kk[i] = (s[i] <= thr) ? k[i] : k1;
        float accs[16];
#pragma unroll
        for (int j = 0; j < 16; ++j) accs[j] = 0.f;
        const float* zb = z + (size_t)(n >> 10) * (CDIM * HW) + (n & 1023);
        for (int c0 = 0; c0 < 256; c0 += 4) {
            float zc0 = zb[(size_t)(c0 + 0) * HW];
            float zc1 = zb[(size_t)(c0 + 1) * HW];
            float zc2 = zb[(size_t)(c0 + 2) * HW];
            float zc3 = zb[(size_t)(c0 + 3) * HW];
#pragma unroll
            for (int j = 0; j < 16; ++j) {
                float4 ev = *(const float4*)&emb[(size_t)kk[j] * CDIM + c0];
                accs[j] = fmaf(zc0, ev.x, accs[j]);
                accs[j] = fmaf(zc1, ev.y, accs[j]);
                accs[j] = fmaf(zc2, ev.z, accs[j]);
                accs[j] = fmaf(zc3, ev.w, accs[j]);
            }
        }
        float bd = FLT_BIG; bk = KCODES;
        const float z2n = z2[n];
#pragma unroll
        for (int j = 0; j < 16; ++j) {
            float d = __fsub_rn(__fadd_rn(z2n, e2[kk[j]]), accs[j] + accs[j]);
            if (lex_lt(d, kk[j], bd, bk)) { bd = d; bk = kk[j]; }
        }
    }
    out_idx_f[n] = (float)bk;
    ws_idx[n] = bk;
}

// ---- kernel 5: gather z_q, write z_q_st, partial loss sums ----
__global__ void __launch_bounds__(256)
gather_kernel(const float* __restrict__ z, const float* __restrict__ emb,
              const int* __restrict__ ws_idx, float* __restrict__ out_zq,
              float* __restrict__ partials) {
    const int t = threadIdx.x;
    const int b = blockIdx.x >> 5;
    const int cg = blockIdx.x & 31;
    const int hw4 = t * 4;

    const int4 iv = *(const int4*)&ws_idx[b * HW + hw4];
    const float* zb = z + (size_t)b * (CDIM * HW) + hw4;
    float* ob = out_zq + (size_t)b * (CDIM * HW) + hw4;
    const float* e0p = emb + (size_t)iv.x * CDIM;
    const float* e1p = emb + (size_t)iv.y * CDIM;
    const float* e2p = emb + (size_t)iv.z * CDIM;
    const float* e3p = emb + (size_t)iv.w * CDIM;

    float lsum = 0.f;
#pragma unroll
    for (int c = cg * 8; c < cg * 8 + 8; ++c) {
        float4 zv = *(const float4*)&zb[(size_t)c * HW];
        float d0 = e0p[c] - zv.x;
        float d1 = e1p[c] - zv.y;
        float d2 = e2p[c] - zv.z;
        float d3 = e3p[c] - zv.w;
        float4 ov = { zv.x + d0, zv.y + d1, zv.z + d2, zv.w + d3 };
        *(float4*)&ob[(size_t)c * HW] = ov;
        lsum = fmaf(d0, d0, lsum);
        lsum = fmaf(d1, d1, lsum);
        lsum = fmaf(d2, d2, lsum);
        lsum = fmaf(d3, d3, lsum);
    }
#pragma unroll
    for (int off = 32; off > 0; off >>= 1) lsum += __shfl_down(lsum, off);
    __shared__ float wsum[4];
    if ((t & 63) == 0) wsum[t >> 6] = lsum;
    __syncthreads();
    if (t == 0) partials[blockIdx.x] = (wsum[0] + wsum[1]) + (wsum[2] + wsum[3]);
}

// ---- kernel 6: finalize loss = 1.25 * mean(diff^2) over 1024 partials ----
__global__ void loss_kernel(const float* __restrict__ partials, float* __restrict__ out_loss) {
    const int t = threadIdx.x;
    float4 v4 = *(const float4*)&partials[t * 4];
    float v = (v4.x + v4.y) + (v4.z + v4.w);
#pragma unroll
    for (int off = 32; off > 0; off >>= 1) v += __shfl_down(v, off);
    __shared__ float wsum[4];
    if ((t & 63) == 0) wsum[t >> 6] = v;
    __syncthreads();
    if (t == 0) {
        float total = (wsum[0] + wsum[1]) + (wsum[2] + wsum[3]);
        out_loss[0] = 1.25f * total / 8388608.0f;
    }
}

extern "C" void kernel_launch(void* const* d_in, const int* in_sizes, int n_in,
                              void* d_out, int out_size, void* d_ws, size_t ws_size,
                              hipStream_t stream) {
    const float* z   = (const float*)d_in[0];
    const float* emb = (const float*)d_in[1];
    float* out = (float*)d_out;

    // A (fp16 [32768][512] = 32 MB) lives in the zq region of d_out; gather overwrites it last.
    f16* A = (f16*)d_out;

    char* w = (char*)d_ws;
    float*  e2       = (float*)(w + 0);            // 4 KB
    float*  z2       = (float*)(w + 4096);         // 128 KB
    f16*    e16      = (f16*)(w + 135168);         // 1 MB
    float4* tile_red = (float4*)(w + 1183744);     // 4 MB
    int*    ws_idx   = (int*)(w + 5378048);        // 128 KB
    float*  partials = (float*)(w + 5509120);      // 4 KB

    hipLaunchKernelGGL(prep_emb_kernel, dim3(128), dim3(256), 0, stream, emb, e2, e16);
    hipLaunchKernelGGL(prep_z_kernel, dim3(1024), dim3(256), 0, stream, z, A, z2);
    hipLaunchKernelGGL(gemm_argmin_kernel, dim3(2048), dim3(256), 0, stream,
                       A, e16, z2, e2, tile_red);
    hipLaunchKernelGGL(rescore_kernel, dim3(128), dim3(256), 0, stream,
                       z, emb, z2, e2, tile_red, out + IDX_OFF, ws_idx);
    hipLaunchKernelGGL(gather_kernel, dim3(1024), dim3(256), 0, stream,
                       z, emb, ws_idx, out, partials);
    hipLaunchKernelGGL(loss_kernel, dim3(1), dim3(256), 0, stream,
                       partials, out + LOSS_OFF);
}

// Round 7
// 294.850 us; speedup vs baseline: 2.3987x; 1.5593x over previous
//
#include <hip/hip_runtime.h>

#define CDIM 256
#define HW 1024            // 32*32
#define NROWS 32768        // 32*1024
#define KCODES 1024
#define ZQ_ELEMS 8388608   // 32*256*1024
#define IDX_OFF ZQ_ELEMS
#define LOSS_OFF (ZQ_ELEMS + NROWS)
#define FLT_BIG 3.402823466e+38f

typedef _Float16 f16;
typedef _Float16 f16x8 __attribute__((ext_vector_type(8)));
typedef float f32x4 __attribute__((ext_vector_type(4)));

// async global->LDS, 16 B per lane; LDS dest = wave-uniform base + lane*16
__device__ __forceinline__ void glds16(const void* g, void* l) {
    __builtin_amdgcn_global_load_lds(
        (const __attribute__((address_space(1))) unsigned int*)g,
        (__attribute__((address_space(3))) unsigned int*)l,
        16, 0, 0);
}

__device__ __forceinline__ unsigned int pack_f16x2(f16 a, f16 b) {
    unsigned short ua = *(unsigned short*)&a, ub = *(unsigned short*)&b;
    return (unsigned int)ua | ((unsigned int)ub << 16);
}

// ---- numpy-bit-exact pairwise sum of squares over 256 contiguous floats ----
__device__ __forceinline__ float np_sumsq_256(const float* __restrict__ a) {
    float half[2];
#pragma unroll
    for (int h = 0; h < 2; ++h) {
        const float* p = a + h * 128;
        float r[8];
#pragma unroll
        for (int j = 0; j < 8; ++j) r[j] = __fmul_rn(p[j], p[j]);
#pragma unroll
        for (int i = 8; i < 128; i += 8) {
#pragma unroll
            for (int j = 0; j < 8; ++j)
                r[j] = __fadd_rn(r[j], __fmul_rn(p[i + j], p[i + j]));
        }
        float ta = __fadd_rn(__fadd_rn(r[0], r[1]), __fadd_rn(r[2], r[3]));
        float tb = __fadd_rn(__fadd_rn(r[4], r[5]), __fadd_rn(r[6], r[7]));
        half[h] = __fadd_rn(ta, tb);
    }
    return __fadd_rn(half[0], half[1]);
}

__device__ __forceinline__ bool lex_lt(float s1, int k1, float s2, int k2) {
    return (s1 < s2) || (s1 == s2 && k1 < k2);
}

__device__ __forceinline__ void top2_merge(float& a1, int& ka1, float& a2, int& ka2,
                                           float b1, int kb1, float b2, int kb2) {
    if (lex_lt(b1, kb1, a1, ka1)) {
        float t1 = a1; int tk1 = ka1;
        a1 = b1; ka1 = kb1;
        if (lex_lt(b2, kb2, t1, tk1)) { a2 = b2; ka2 = kb2; }
        else                          { a2 = t1; ka2 = tk1; }
    } else {
        if (lex_lt(b1, kb1, a2, ka2)) { a2 = b1; ka2 = kb1; }
    }
}

// ---- kernel 1: fused emb prep: e16 conversion + e2 (np-exact) ----
__global__ void __launch_bounds__(256)
prep_emb_kernel(const float* __restrict__ emb, float* __restrict__ e2, f16* __restrict__ e16) {
    const int gid = blockIdx.x * 256 + threadIdx.x;   // 0..32767
    const int k = gid >> 5, seg = gid & 31;           // seg covers 8 c
    const float* src = emb + (size_t)k * CDIM + seg * 8;
    float4 v0 = *(const float4*)src;
    float4 v1 = *(const float4*)(src + 4);
    float s[8] = { v0.x, v0.y, v0.z, v0.w, v1.x, v1.y, v1.z, v1.w };
    f16 h[8], l[8];
#pragma unroll
    for (int j = 0; j < 8; ++j) {
        float sv = s[j] * 1024.0f;
        h[j] = (f16)sv;
        float r = __fsub_rn(sv, (float)h[j]);
        l[j] = (f16)r;
    }
    uint4 hv, lv;
    hv.x = pack_f16x2(h[0], h[1]); hv.y = pack_f16x2(h[2], h[3]);
    hv.z = pack_f16x2(h[4], h[5]); hv.w = pack_f16x2(h[6], h[7]);
    lv.x = pack_f16x2(l[0], l[1]); lv.y = pack_f16x2(l[2], l[3]);
    lv.z = pack_f16x2(l[4], l[5]); lv.w = pack_f16x2(l[6], l[7]);
    *(uint4*)(e16 + (size_t)k * 512 + seg * 8) = hv;
    *(uint4*)(e16 + (size_t)k * 512 + 256 + seg * 8) = lv;
    if (seg == 0) e2[k] = np_sumsq_256(emb + (size_t)k * CDIM);
}

// ---- kernel 2: z prep: z2 (np-exact) + A[n][512] = [z_hi|z_lo] fp16, z scaled by 16 ----
__global__ void __launch_bounds__(256)
prep_z_kernel(const float* __restrict__ z, f16* __restrict__ A, float* __restrict__ z2) {
    __shared__ __align__(16) float z_lds[32 * 260];
    const int t = threadIdx.x;
    const int n0 = blockIdx.x * 32;
    const int b = n0 >> 10, hw0 = n0 & 1023;
    const float* zbase = z + (size_t)b * (CDIM * HW) + hw0;
#pragma unroll
    for (int p = 0; p < 8; ++p) {
        int id = p * 256 + t;
        int c = id >> 3;
        int m4 = id & 7;
        float4 v = *(const float4*)(zbase + (size_t)c * HW + m4 * 4);
        z_lds[(m4 * 4 + 0) * 260 + c] = v.x;
        z_lds[(m4 * 4 + 1) * 260 + c] = v.y;
        z_lds[(m4 * 4 + 2) * 260 + c] = v.z;
        z_lds[(m4 * 4 + 3) * 260 + c] = v.w;
    }
    __syncthreads();
    if (t < 32) z2[n0 + t] = np_sumsq_256(&z_lds[t * 260]);

    const int lane = t & 63, wave = t >> 6;
    const int half = lane >> 5;       // 0 = hi, 1 = lo
    const int seg = lane & 31;        // 8 c per seg
#pragma unroll
    for (int rr = 0; rr < 8; ++rr) {
        const int m = wave * 8 + rr;
        const float* zr = &z_lds[m * 260 + seg * 8];
        f16 o[8];
#pragma unroll
        for (int j = 0; j < 8; ++j) {
            float sv = zr[j] * 16.0f;
            f16 hh = (f16)sv;
            if (half) {
                float r = __fsub_rn(sv, (float)hh);
                o[j] = (f16)r;
            } else {
                o[j] = hh;
            }
        }
        uint4 ov;
        ov.x = pack_f16x2(o[0], o[1]); ov.y = pack_f16x2(o[2], o[3]);
        ov.z = pack_f16x2(o[4], o[5]); ov.w = pack_f16x2(o[6], o[7]);
        *(uint4*)(A + (size_t)(n0 + m) * 512 + half * 256 + seg * 8) = ov;
    }
}

// ---- kernel 3: MFMA GEMM + per-row-per-tile top2 (m97-structure async pipeline) ----
// Block 256 thr / 4 waves, tile 128 rows x 128 codes. Grid 2048:
// Mtile = bid&255, Ntile = bid>>8. 16 iters of BK=32 f16 (64 B/row).
// Per iter: issue global_load_lds chunk kk+1 -> buf^1, compute buf, barrier.
// Barrier drain lands AFTER ~300 cyc of compute -> latency hidden (m97).
// acc = dot * 2^14 -> 2*dot = acc * 2^-13.
__global__ void __launch_bounds__(256, 2)
gemm_argmin_kernel(const f16* __restrict__ A, const f16* __restrict__ B,
                   const float* __restrict__ z2, const float* __restrict__ e2,
                   float4* __restrict__ tile_red) {
    __shared__ __align__(16) f16 a_lds[2][128 * 32];    // 2 x 8 KB
    __shared__ __align__(16) f16 b1_lds[2][128 * 32];   // 2 x 8 KB
    __shared__ __align__(16) f16 b2_lds[2][128 * 32];   // 2 x 8 KB
    __shared__ __align__(16) float4 red_lds[4 * 64];    // 4 KB

    const int t = threadIdx.x;
    const int lane = t & 63, wave = t >> 6;
    const int Mtile = blockIdx.x & 255, Ntile = blockIdx.x >> 8;
    const int wm = (wave >> 1) * 64, wn = (wave & 1) * 64;
    const int l15 = lane & 15, quad = lane >> 4;

    // staging: wave handles segments s0=2w, s1=2w+1 (each 1 KB = 16 rows x 64 B)
    // lane -> row 16s + (lane>>2), 16B piece (lane&3); LDS dest = base + lane*16
    const int s0 = 2 * wave, s1 = s0 + 1;
    const char* Abase = (const char*)(A + (size_t)Mtile * 128 * 512);
    const char* Bbase = (const char*)(B + (size_t)Ntile * 128 * 512);
    const int lrow = lane >> 2, lseg = (lane & 3) * 16;
    const char* ag0 = Abase + (size_t)(s0 * 16 + lrow) * 1024 + lseg;
    const char* ag1 = Abase + (size_t)(s1 * 16 + lrow) * 1024 + lseg;
    const char* bg0 = Bbase + (size_t)(s0 * 16 + lrow) * 1024 + lseg;
    const char* bg1 = Bbase + (size_t)(s1 * 16 + lrow) * 1024 + lseg;

    f32x4 acc[4][4] = {};

    // preload chunk 0 into buf 0
    glds16(ag0,       &a_lds[0][s0 * 512]);
    glds16(ag1,       &a_lds[0][s1 * 512]);
    glds16(bg0,       &b1_lds[0][s0 * 512]);
    glds16(bg1,       &b1_lds[0][s1 * 512]);
    glds16(bg0 + 512, &b2_lds[0][s0 * 512]);
    glds16(bg1 + 512, &b2_lds[0][s1 * 512]);
    __syncthreads();   // vmcnt(0) drain: chunk 0 resident

    for (int kk = 0; kk < 16; ++kk) {
        const int buf = kk & 1;
        if (kk < 15) {
            const int nb = buf ^ 1;
            const int ko = (kk + 1) * 64;            // byte offset in 1024-B row
            const int ko2 = (ko + 512) & 1023;
            glds16(ag0 + ko,  &a_lds[nb][s0 * 512]);
            glds16(ag1 + ko,  &a_lds[nb][s1 * 512]);
            glds16(bg0 + ko,  &b1_lds[nb][s0 * 512]);
            glds16(bg1 + ko,  &b1_lds[nb][s1 * 512]);
            glds16(bg0 + ko2, &b2_lds[nb][s0 * 512]);
            glds16(bg1 + ko2, &b2_lds[nb][s1 * 512]);
        }

        f16x8 af[4];
#pragma unroll
        for (int i = 0; i < 4; ++i)
            af[i] = *(const f16x8*)&a_lds[buf][(wm + i * 16 + l15) * 32 + quad * 8];
#pragma unroll
        for (int ph = 0; ph < 2; ++ph) {
            const f16* bl = ph ? b2_lds[buf] : b1_lds[buf];
            f16x8 bf[4];
#pragma unroll
            for (int j = 0; j < 4; ++j)
                bf[j] = *(const f16x8*)&bl[(wn + j * 16 + l15) * 32 + quad * 8];
#pragma unroll
            for (int i = 0; i < 4; ++i)
#pragma unroll
                for (int j = 0; j < 4; ++j)
                    acc[i][j] = __builtin_amdgcn_mfma_f32_16x16x32_f16(af[i], bf[j], acc[i][j], 0, 0, 0);
        }
        __syncthreads();   // drains vmcnt: chunk kk+1 resident; buf^1 safe to read next iter
    }

    // ---- epilogue: d = fl(fl(z2+e2) - fl(acc*2^-13)); per-(i,r) top2 ----
    float e2v[4];
#pragma unroll
    for (int j = 0; j < 4; ++j) e2v[j] = e2[Ntile * 128 + wn + j * 16 + l15];

    float S1[4][4], S2[4][4];
    int   K1v[4][4], K2v[4][4];
#pragma unroll
    for (int i = 0; i < 4; ++i) {
        float z2q[4];
#pragma unroll
        for (int r = 0; r < 4; ++r)
            z2q[r] = z2[Mtile * 128 + wm + i * 16 + quad * 4 + r];
#pragma unroll
        for (int r = 0; r < 4; ++r) {
            float s1 = FLT_BIG, s2 = FLT_BIG;
            int k1 = KCODES, k2 = KCODES;
#pragma unroll
            for (int j = 0; j < 4; ++j) {
                float d = __fsub_rn(__fadd_rn(z2q[r], e2v[j]),
                                    __fmul_rn(acc[i][j][r], 1.220703125e-4f));
                int kc = Ntile * 128 + wn + j * 16 + l15;
                if (lex_lt(d, kc, s1, k1)) { s2 = s1; k2 = k1; s1 = d; k1 = kc; }
                else if (lex_lt(d, kc, s2, k2)) { s2 = d; k2 = kc; }
            }
            S1[i][r] = s1; K1v[i][r] = k1; S2[i][r] = s2; K2v[i][r] = k2;
        }
    }

#pragma unroll
    for (int mask = 1; mask <= 8; mask <<= 1) {
#pragma unroll
        for (int i = 0; i < 4; ++i)
#pragma unroll
            for (int r = 0; r < 4; ++r) {
                float b1 = __shfl_xor(S1[i][r], mask);
                int  kb1 = __shfl_xor(K1v[i][r], mask);
                float b2 = __shfl_xor(S2[i][r], mask);
                int  kb2 = __shfl_xor(K2v[i][r], mask);
                top2_merge(S1[i][r], K1v[i][r], S2[i][r], K2v[i][r], b1, kb1, b2, kb2);
            }
    }

    if (l15 == 0) {
#pragma unroll
        for (int i = 0; i < 4; ++i)
#pragma unroll
            for (int r = 0; r < 4; ++r) {
                float4 st;
                st.x = S1[i][r]; st.y = __int_as_float(K1v[i][r]);
                st.z = S2[i][r]; st.w = __int_as_float(K2v[i][r]);
                red_lds[wave * 64 + i * 16 + quad * 4 + r] = st;
            }
    }
    __syncthreads();
    if (t < 128) {
        int wA = (t >> 6) * 2, rw = t & 63;
        float4 a = red_lds[wA * 64 + rw];
        float4 b = red_lds[(wA + 1) * 64 + rw];
        float a1 = a.x, a2 = a.z; int ka1 = __float_as_int(a.y), ka2 = __float_as_int(a.w);
        top2_merge(a1, ka1, a2, ka2, b.x, __float_as_int(b.y), b.z, __float_as_int(b.w));
        float4 o;
        o.x = a1; o.y = __int_as_float(ka1); o.z = a2; o.w = __int_as_float(ka2);
        tile_red[(size_t)(Mtile * 128 + t) * 8 + Ntile] = o;
    }
}

// ---- kernel 4: candidate reduce + exact fp32 rescore (margin 1e-4, verified) ----
__global__ void __launch_bounds__(64)
rescore_kernel(const float* __restrict__ z, const float* __restrict__ emb,
               const float* __restrict__ z2, const float* __restrict__ e2,
               const float4* __restrict__ tile_red, float* __restrict__ out_idx_f,
               int* __restrict__ ws_idx) {
    const int n = blockIdx.x * 64 + threadIdx.x;
    float s[16]; int k[16];
#pragma unroll
    for (int i = 0; i < 8; ++i) {
        float4 v = tile_red[(size_t)n * 8 + i];
        s[2 * i] = v.x;     k[2 * i] = __float_as_int(v.y);
        s[2 * i + 1] = v.z; k[2 * i + 1] = __float_as_int(v.w);
    }
    float s1 = FLT_BIG; int k1 = KCODES;
#pragma unroll
    for (int i = 0; i < 16; ++i)
        if (lex_lt(s[i], k[i], s1, k1)) { s1 = s[i]; k1 = k[i]; }
    const float thr = s1 + 1.0e-4f;
    int cnt = 0;
#pragma unroll
    for (int i = 0; i < 16; ++i) cnt += (s[i] <= thr) ? 1 : 0;

    int bk = k1;
    if (cnt > 1) {
        int kk[16];
#pragma unroll
        for (int i = 0; i < 16; ++i) kk[i] = (s[i] <= thr) ? k[i] : k1;
        float accs[16];
#pragma unroll
        for (int j = 0; j < 16; ++j) accs[j] = 0.f;
        const float* zb = z + (size_t)(n >> 10) * (CDIM * HW) + (n & 1023);
        for (int c0 = 0; c0 < 256; c0 += 4) {
            float zc0 = zb[(size_t)(c0 + 0) * HW];
            float zc1 = zb[(size_t)(c0 + 1) * HW];
            float zc2 = zb[(size_t)(c0 + 2) * HW];
            float zc3 = zb[(size_t)(c0 + 3) * HW];
#pragma unroll
            for (int j = 0; j < 16; ++j) {
                float4 ev = *(const float4*)&emb[(size_t)kk[j] * CDIM + c0];
                accs[j] = fmaf(zc0, ev.x, accs[j]);
                accs[j] = fmaf(zc1, ev.y, accs[j]);
                accs[j] = fmaf(zc2, ev.z, accs[j]);
                accs[j] = fmaf(zc3, ev.w, accs[j]);
            }
        }
        float bd = FLT_BIG; bk = KCODES;
        const float z2n = z2[n];
#pragma unroll
        for (int j = 0; j < 16; ++j) {
            float d = __fsub_rn(__fadd_rn(z2n, e2[kk[j]]), accs[j] + accs[j]);
            if (lex_lt(d, kk[j], bd, bk)) { bd = d; bk = kk[j]; }
        }
    }
    out_idx_f[n] = (float)bk;
    ws_idx[n] = bk;
}

// ---- kernel 5: gather z_q, write z_q_st, partial loss sums ----
__global__ void __launch_bounds__(256)
gather_kernel(const float* __restrict__ z, const float* __restrict__ emb,
              const int* __restrict__ ws_idx, float* __restrict__ out_zq,
              float* __restrict__ partials) {
    const int t = threadIdx.x;
    const int b = blockIdx.x >> 5;
    const int cg = blockIdx.x & 31;
    const int hw4 = t * 4;

    const int4 iv = *(const int4*)&ws_idx[b * HW + hw4];
    const float* zb = z + (size_t)b * (CDIM * HW) + hw4;
    float* ob = out_zq + (size_t)b * (CDIM * HW) + hw4;
    const float* e0p = emb + (size_t)iv.x * CDIM;
    const float* e1p = emb + (size_t)iv.y * CDIM;
    const float* e2p = emb + (size_t)iv.z * CDIM;
    const float* e3p = emb + (size_t)iv.w * CDIM;

    float lsum = 0.f;
#pragma unroll
    for (int c = cg * 8; c < cg * 8 + 8; ++c) {
        float4 zv = *(const float4*)&zb[(size_t)c * HW];
        float d0 = e0p[c] - zv.x;
        float d1 = e1p[c] - zv.y;
        float d2 = e2p[c] - zv.z;
        float d3 = e3p[c] - zv.w;
        float4 ov = { zv.x + d0, zv.y + d1, zv.z + d2, zv.w + d3 };
        *(float4*)&ob[(size_t)c * HW] = ov;
        lsum = fmaf(d0, d0, lsum);
        lsum = fmaf(d1, d1, lsum);
        lsum = fmaf(d2, d2, lsum);
        lsum = fmaf(d3, d3, lsum);
    }
#pragma unroll
    for (int off = 32; off > 0; off >>= 1) lsum += __shfl_down(lsum, off);
    __shared__ float wsum[4];
    if ((t & 63) == 0) wsum[t >> 6] = lsum;
    __syncthreads();
    if (t == 0) partials[blockIdx.x] = (wsum[0] + wsum[1]) + (wsum[2] + wsum[3]);
}

// ---- kernel 6: finalize loss = 1.25 * mean(diff^2) over 1024 partials ----
__global__ void loss_kernel(const float* __restrict__ partials, float* __restrict__ out_loss) {
    const int t = threadIdx.x;
    float4 v4 = *(const float4*)&partials[t * 4];
    float v = (v4.x + v4.y) + (v4.z + v4.w);
#pragma unroll
    for (int off = 32; off > 0; off >>= 1) v += __shfl_down(v, off);
    __shared__ float wsum[4];
    if ((t & 63) == 0) wsum[t >> 6] = v;
    __syncthreads();
    if (t == 0) {
        float total = (wsum[0] + wsum[1]) + (wsum[2] + wsum[3]);
        out_loss[0] = 1.25f * total / 8388608.0f;
    }
}

extern "C" void kernel_launch(void* const* d_in, const int* in_sizes, int n_in,
                              void* d_out, int out_size, void* d_ws, size_t ws_size,
                              hipStream_t stream) {
    const float* z   = (const float*)d_in[0];
    const float* emb = (const float*)d_in[1];
    float* out = (float*)d_out;

    // A (fp16 [32768][512] = 32 MB) lives in the zq region of d_out; gather overwrites it last.
    f16* A = (f16*)d_out;

    char* w = (char*)d_ws;
    float*  e2       = (float*)(w + 0);            // 4 KB
    float*  z2       = (float*)(w + 4096);         // 128 KB
    f16*    e16      = (f16*)(w + 135168);         // 1 MB
    float4* tile_red = (float4*)(w + 1183744);     // 4 MB
    int*    ws_idx   = (int*)(w + 5378048);        // 128 KB
    float*  partials = (float*)(w + 5509120);      // 4 KB

    hipLaunchKernelGGL(prep_emb_kernel, dim3(128), dim3(256), 0, stream, emb, e2, e16);
    hipLaunchKernelGGL(prep_z_kernel, dim3(1024), dim3(256), 0, stream, z, A, z2);
    hipLaunchKernelGGL(gemm_argmin_kernel, dim3(2048), dim3(256), 0, stream,
                       A, e16, z2, e2, tile_red);
    hipLaunchKernelGGL(rescore_kernel, dim3(512), dim3(64), 0, stream,
                       z, emb, z2, e2, tile_red, out + IDX_OFF, ws_idx);
    hipLaunchKernelGGL(gather_kernel, dim3(1024), dim3(256), 0, stream,
                       z, emb, ws_idx, out, partials);
    hipLaunchKernelGGL(loss_kernel, dim3(1), dim3(256), 0, stream,
                       partials, out + LOSS_OFF);
}